// Round 1
// baseline (4430.785 us; speedup 1.0000x reference)
//
#include <hip/hip_runtime.h>

#define GROUPS 2
#define NUM_VARS 320
#define NVT 640          // GROUPS*NUM_VARS
#define DIM 512
#define VAR_DIM 128
#define NTOK 48000       // B*T
#define TM 32            // tokens per block
#define KC 16            // K-chunk
#define BLOCK 256

// Reorder W[640][512] -> Wq[k/4][640][4] so a K-chunk is one contiguous slab
// and inner-loop float4 LDS reads are consecutive-lane-consecutive-address.
__global__ void make_wq_kernel(const float* __restrict__ W, float* __restrict__ Wq) {
    int f = blockIdx.x * blockDim.x + threadIdx.x;
    if (f >= NVT * DIM) return;
    int kl = f & 3;
    int v  = (f >> 2) % NVT;
    int kq = f / (NVT * 4);
    Wq[f] = W[(size_t)v * DIM + kq * 4 + kl];
}

template <bool USE_WQ>
__global__ void vq_main_kernel(const float* __restrict__ x,
                               const float* __restrict__ W,
                               const float* __restrict__ Wq,
                               const float* __restrict__ bias,
                               const float* __restrict__ codebook,
                               float* __restrict__ out,
                               float* __restrict__ avg_out) {
    __shared__ float w_s[KC * NVT];   // layout [kq][v][4]  (40 KB)
    __shared__ float x_s[TM][KC];     // [tok][kk]          (2 KB)
    __shared__ float avg_s[NVT];      // block partial softmax sums

    const int tid = threadIdx.x;
    const int tx  = tid & 63;         // lane
    const int ty  = tid >> 6;         // wave id 0..3
    const int n0  = blockIdx.x * TM;

    float acc[8][10];
#pragma unroll
    for (int t = 0; t < 8; ++t)
#pragma unroll
        for (int j = 0; j < 10; ++j) acc[t][j] = 0.f;

    for (int i = tid; i < NVT; i += BLOCK) avg_s[i] = 0.f;

    for (int k0 = 0; k0 < DIM; k0 += KC) {
        __syncthreads();
        if (USE_WQ) {
            const float4* src = (const float4*)(Wq + (size_t)k0 * NVT);
            float4* dst = (float4*)w_s;
#pragma unroll
            for (int i = 0; i < KC * NVT / 4 / BLOCK; ++i)   // 10 float4 each
                dst[tid + i * BLOCK] = src[tid + i * BLOCK];
        } else {
            // fallback: scratch too small for Wq — strided reads (slow, correct)
            for (int i = tid; i < KC * NVT; i += BLOCK) {
                int kl = i & 3;
                int v  = (i >> 2) % NVT;
                int kq = i / (NVT * 4);
                w_s[i] = W[(size_t)v * DIM + k0 + kq * 4 + kl];
            }
        }
        {
            int tok = tid >> 2, q = tid & 3;
            if (tid < TM * 4)
                *(float4*)&x_s[tok][q * 4] =
                    *(const float4*)(x + (size_t)(n0 + tok) * DIM + k0 + q * 4);
        }
        __syncthreads();

        const float4* w4 = (const float4*)w_s;
#pragma unroll
        for (int kq = 0; kq < KC / 4; ++kq) {
            float4 wv[10];
#pragma unroll
            for (int j = 0; j < 10; ++j) wv[j] = w4[kq * NVT + tx + 64 * j];
#pragma unroll
            for (int t = 0; t < 8; ++t) {
                float4 xv = *(const float4*)&x_s[ty * 8 + t][kq * 4];
#pragma unroll
                for (int j = 0; j < 10; ++j) {
                    acc[t][j] = fmaf(xv.x, wv[j].x, acc[t][j]);
                    acc[t][j] = fmaf(xv.y, wv[j].y, acc[t][j]);
                    acc[t][j] = fmaf(xv.z, wv[j].z, acc[t][j]);
                    acc[t][j] = fmaf(xv.w, wv[j].w, acc[t][j]);
                }
            }
        }
    }

    // bias (zeros in harness, kept for generality)
#pragma unroll
    for (int j = 0; j < 10; ++j) {
        float bv = bias[tx + 64 * j];
#pragma unroll
        for (int t = 0; t < 8; ++t) acc[t][j] += bv;
    }

    // Epilogue: each wave owns 8 tokens (all 640 vars spread over its 64 lanes).
    for (int t = 0; t < 8; ++t) {
        const int n = n0 + ty * 8 + t;
#pragma unroll
        for (int g = 0; g < GROUPS; ++g) {
            // local top-2 over this lane's 5 values of group g
            float v1 = -3.4e38f, v2 = -3.4e38f;
            int   i1 = 0x7fffffff, i2 = 0x7fffffff;
#pragma unroll
            for (int jj = 0; jj < 5; ++jj) {
                float val = acc[t][g * 5 + jj];
                int   vv  = tx + 64 * jj;      // index within group
                if ((val > v1) || (val == v1 && vv < i1)) {
                    v2 = v1; i2 = i1; v1 = val; i1 = vv;
                } else if ((val > v2) || (val == v2 && vv < i2)) {
                    v2 = val; i2 = vv;
                }
            }
            // wave butterfly top-2 merge
#pragma unroll
            for (int off = 32; off >= 1; off >>= 1) {
                float o1 = __shfl_xor(v1, off);
                int  oi1 = __shfl_xor(i1, off);
                float o2 = __shfl_xor(v2, off);
                int  oi2 = __shfl_xor(i2, off);
                if ((o1 > v1) || (o1 == v1 && oi1 < i1)) { v2 = v1; i2 = i1; v1 = o1; i1 = oi1; }
                else if ((o1 > v2) || (o1 == v2 && oi1 < i2)) { v2 = o1; i2 = oi1; }
                if ((o2 > v1) || (o2 == v1 && oi2 < i1)) { v2 = v1; i2 = i1; v1 = o2; i1 = oi2; }
                else if ((o2 > v2) || (o2 == v2 && oi2 < i2)) { v2 = o2; i2 = oi2; }
            }

            // softmax (fp32, max = v1)
            float m = v1, e[5], s = 0.f;
#pragma unroll
            for (int jj = 0; jj < 5; ++jj) {
                e[jj] = expf(acc[t][g * 5 + jj] - m);
                s += e[jj];
            }
#pragma unroll
            for (int off = 32; off >= 1; off >>= 1) s += __shfl_xor(s, off);
            float inv = 1.f / s;
#pragma unroll
            for (int jj = 0; jj < 5; ++jj)
                atomicAdd(&avg_s[g * NUM_VARS + tx + 64 * jj], e[jj] * inv);

            // f64 re-verification of the top-2 candidates (argmax robustness)
            const float* xrow = x + (size_t)n * DIM;
            const float* w1r  = W + (size_t)(g * NUM_VARS + i1) * DIM;
            const float* w2r  = W + (size_t)(g * NUM_VARS + i2) * DIM;
            double d1 = 0.0, d2 = 0.0;
            for (int k = tx; k < DIM; k += 64) {
                double xv = (double)xrow[k];
                d1 += xv * (double)w1r[k];
                d2 += xv * (double)w2r[k];
            }
#pragma unroll
            for (int off = 32; off >= 1; off >>= 1) {
                d1 += __shfl_xor(d1, off);
                d2 += __shfl_xor(d2, off);
            }
            d1 += (double)bias[g * NUM_VARS + i1];
            d2 += (double)bias[g * NUM_VARS + i2];
            const int kbest = (d2 > d1 || (d2 == d1 && i2 < i1)) ? i2 : i1;

            // gather codebook row -> out (float2 per lane, coalesced 512B)
            const float2 cbv = *(const float2*)(codebook +
                                (size_t)(g * NUM_VARS + kbest) * VAR_DIM + 2 * tx);
            *(float2*)(out + (size_t)n * (GROUPS * VAR_DIM) + g * VAR_DIM + 2 * tx) = cbv;
        }
    }

    __syncthreads();
    const float scale = 1.f / (float)NTOK;
    for (int i = tid; i < NVT; i += BLOCK)
        atomicAdd(&avg_out[i], avg_s[i] * scale);
}

extern "C" void kernel_launch(void* const* d_in, const int* in_sizes, int n_in,
                              void* d_out, int out_size, void* d_ws, size_t ws_size,
                              hipStream_t stream) {
    const float* x  = (const float*)d_in[0];
    const float* W  = (const float*)d_in[1];
    const float* b  = (const float*)d_in[2];
    const float* cb = (const float*)d_in[3];
    float* out = (float*)d_out;
    float* avg = out + (size_t)NTOK * GROUPS * VAR_DIM;   // avg_probs tail [2*320]

    hipMemsetAsync(avg, 0, NVT * sizeof(float), stream);

    const size_t wq_bytes = (size_t)NVT * DIM * sizeof(float);
    if (ws_size >= wq_bytes) {
        float* Wq = (float*)d_ws;
        make_wq_kernel<<<(NVT * DIM + 255) / 256, 256, 0, stream>>>(W, Wq);
        vq_main_kernel<true><<<NTOK / TM, BLOCK, 0, stream>>>(x, W, Wq, b, cb, out, avg);
    } else {
        vq_main_kernel<false><<<NTOK / TM, BLOCK, 0, stream>>>(x, W, nullptr, b, cb, out, avg);
    }
}

// Round 2
// 2052.892 us; speedup vs baseline: 2.1583x; 2.1583x over previous
//
#include <hip/hip_runtime.h>

#define GROUPS 2
#define NUM_VARS 320
#define NVT 640          // GROUPS*NUM_VARS
#define DIM 512
#define VAR_DIM 128
#define NTOK 48000       // B*T
#define TM 32            // tokens per block
#define KC 16            // K-chunk
#define BLOCK 256

// Reorder W[640][512] -> Wq[k/4][640][4] so a K-chunk is one contiguous slab
// and inner-loop float4 LDS reads are consecutive-lane-consecutive-address.
__global__ void make_wq_kernel(const float* __restrict__ W, float* __restrict__ Wq) {
    int f = blockIdx.x * blockDim.x + threadIdx.x;
    if (f >= NVT * DIM) return;
    int kl = f & 3;
    int v  = (f >> 2) % NVT;
    int kq = f / (NVT * 4);
    Wq[f] = W[(size_t)v * DIM + kq * 4 + kl];
}

template <bool USE_WQ>
__global__ void vq_main_kernel(const float* __restrict__ x,
                               const float* __restrict__ W,
                               const float* __restrict__ Wq,
                               const float* __restrict__ bias,
                               const float* __restrict__ codebook,
                               float* __restrict__ out,
                               float* __restrict__ avg_out) {
    __shared__ float w_s[KC * NVT];   // layout [kq][v][4]  (40 KB)
    __shared__ float x_s[TM][KC];     // [tok][kk]          (2 KB)
    __shared__ float avg_s[NVT];      // block partial softmax sums

    const int tid = threadIdx.x;
    const int tx  = tid & 63;         // lane
    const int ty  = tid >> 6;         // wave id 0..3
    const int n0  = blockIdx.x * TM;

    float acc[8][10];
#pragma unroll
    for (int t = 0; t < 8; ++t)
#pragma unroll
        for (int j = 0; j < 10; ++j) acc[t][j] = 0.f;

    for (int i = tid; i < NVT; i += BLOCK) avg_s[i] = 0.f;

    for (int k0 = 0; k0 < DIM; k0 += KC) {
        __syncthreads();
        if (USE_WQ) {
            const float4* src = (const float4*)(Wq + (size_t)k0 * NVT);
            float4* dst = (float4*)w_s;
#pragma unroll
            for (int i = 0; i < KC * NVT / 4 / BLOCK; ++i)   // 10 float4 each
                dst[tid + i * BLOCK] = src[tid + i * BLOCK];
        } else {
            // fallback: scratch too small for Wq — strided reads (slow, correct)
            for (int i = tid; i < KC * NVT; i += BLOCK) {
                int kl = i & 3;
                int v  = (i >> 2) % NVT;
                int kq = i / (NVT * 4);
                w_s[i] = W[(size_t)v * DIM + k0 + kq * 4 + kl];
            }
        }
        {
            int tok = tid >> 2, q = tid & 3;
            if (tid < TM * 4)
                *(float4*)&x_s[tok][q * 4] =
                    *(const float4*)(x + (size_t)(n0 + tok) * DIM + k0 + q * 4);
        }
        __syncthreads();

        const float4* w4 = (const float4*)w_s;
#pragma unroll
        for (int kq = 0; kq < KC / 4; ++kq) {
            float4 wv[10];
#pragma unroll
            for (int j = 0; j < 10; ++j) wv[j] = w4[kq * NVT + tx + 64 * j];
#pragma unroll
            for (int t = 0; t < 8; ++t) {
                float4 xv = *(const float4*)&x_s[ty * 8 + t][kq * 4];
#pragma unroll
                for (int j = 0; j < 10; ++j) {
                    acc[t][j] = fmaf(xv.x, wv[j].x, acc[t][j]);
                    acc[t][j] = fmaf(xv.y, wv[j].y, acc[t][j]);
                    acc[t][j] = fmaf(xv.z, wv[j].z, acc[t][j]);
                    acc[t][j] = fmaf(xv.w, wv[j].w, acc[t][j]);
                }
            }
        }
    }

    // bias (zeros in harness, kept for generality)
#pragma unroll
    for (int j = 0; j < 10; ++j) {
        float bv = bias[tx + 64 * j];
#pragma unroll
        for (int t = 0; t < 8; ++t) acc[t][j] += bv;
    }

    // Epilogue: each wave owns 8 tokens (all 640 vars spread over its 64 lanes).
    // MUST be fully unrolled: any runtime index into acc[] demotes it to scratch
    // (rule #20 — R1 measured 19.8 GB of HBM scratch writes from exactly this).
#pragma unroll
    for (int t = 0; t < 8; ++t) {
        const int n = n0 + ty * 8 + t;
#pragma unroll
        for (int g = 0; g < GROUPS; ++g) {
            // local top-2 over this lane's 5 values of group g
            float v1 = -3.4e38f, v2 = -3.4e38f;
            int   i1 = 0x7fffffff, i2 = 0x7fffffff;
#pragma unroll
            for (int jj = 0; jj < 5; ++jj) {
                float val = acc[t][g * 5 + jj];
                int   vv  = tx + 64 * jj;      // index within group
                if ((val > v1) || (val == v1 && vv < i1)) {
                    v2 = v1; i2 = i1; v1 = val; i1 = vv;
                } else if ((val > v2) || (val == v2 && vv < i2)) {
                    v2 = val; i2 = vv;
                }
            }
            // wave butterfly top-2 merge
#pragma unroll
            for (int off = 32; off >= 1; off >>= 1) {
                float o1 = __shfl_xor(v1, off);
                int  oi1 = __shfl_xor(i1, off);
                float o2 = __shfl_xor(v2, off);
                int  oi2 = __shfl_xor(i2, off);
                if ((o1 > v1) || (o1 == v1 && oi1 < i1)) { v2 = v1; i2 = i1; v1 = o1; i1 = oi1; }
                else if ((o1 > v2) || (o1 == v2 && oi1 < i2)) { v2 = o1; i2 = oi1; }
                if ((o2 > v1) || (o2 == v1 && oi2 < i1)) { v2 = v1; i2 = i1; v1 = o2; i1 = oi2; }
                else if ((o2 > v2) || (o2 == v2 && oi2 < i2)) { v2 = o2; i2 = oi2; }
            }

            // softmax (fp32, max = v1)
            float m = v1, s = 0.f;
            float e[5];
#pragma unroll
            for (int jj = 0; jj < 5; ++jj) {
                e[jj] = expf(acc[t][g * 5 + jj] - m);
                s += e[jj];
            }
#pragma unroll
            for (int off = 32; off >= 1; off >>= 1) s += __shfl_xor(s, off);
            float inv = 1.f / s;
#pragma unroll
            for (int jj = 0; jj < 5; ++jj)
                atomicAdd(&avg_s[g * NUM_VARS + tx + 64 * jj], e[jj] * inv);

            // Argmax robustness: fp32 summation-order noise is ~1e-3 while the
            // typical top1-top2 gap is ~6.6 (logits sigma ~22.6). Only when the
            // gap is tiny do we re-verify the two candidates in f64. v1/v2 are
            // wave-uniform after the butterfly -> uniform branch, ~0.8% taken.
            int kbest = i1;
            if (v1 - v2 <= 0.05f) {
                const float* xrow = x + (size_t)n * DIM;
                const float* w1r  = W + (size_t)(g * NUM_VARS + i1) * DIM;
                const float* w2r  = W + (size_t)(g * NUM_VARS + i2) * DIM;
                double d1 = 0.0, d2 = 0.0;
                for (int k = tx; k < DIM; k += 64) {
                    double xv = (double)xrow[k];
                    d1 += xv * (double)w1r[k];
                    d2 += xv * (double)w2r[k];
                }
#pragma unroll
                for (int off = 32; off >= 1; off >>= 1) {
                    d1 += __shfl_xor(d1, off);
                    d2 += __shfl_xor(d2, off);
                }
                d1 += (double)bias[g * NUM_VARS + i1];
                d2 += (double)bias[g * NUM_VARS + i2];
                kbest = (d2 > d1 || (d2 == d1 && i2 < i1)) ? i2 : i1;
            }

            // gather codebook row -> out (float2 per lane, coalesced 512B)
            const float2 cbv = *(const float2*)(codebook +
                                (size_t)(g * NUM_VARS + kbest) * VAR_DIM + 2 * tx);
            *(float2*)(out + (size_t)n * (GROUPS * VAR_DIM) + g * VAR_DIM + 2 * tx) = cbv;
        }
    }

    __syncthreads();
    const float scale = 1.f / (float)NTOK;
    for (int i = tid; i < NVT; i += BLOCK)
        atomicAdd(&avg_out[i], avg_s[i] * scale);
}

extern "C" void kernel_launch(void* const* d_in, const int* in_sizes, int n_in,
                              void* d_out, int out_size, void* d_ws, size_t ws_size,
                              hipStream_t stream) {
    const float* x  = (const float*)d_in[0];
    const float* W  = (const float*)d_in[1];
    const float* b  = (const float*)d_in[2];
    const float* cb = (const float*)d_in[3];
    float* out = (float*)d_out;
    float* avg = out + (size_t)NTOK * GROUPS * VAR_DIM;   // avg_probs tail [2*320]

    hipMemsetAsync(avg, 0, NVT * sizeof(float), stream);

    const size_t wq_bytes = (size_t)NVT * DIM * sizeof(float);
    if (ws_size >= wq_bytes) {
        float* Wq = (float*)d_ws;
        make_wq_kernel<<<(NVT * DIM + 255) / 256, 256, 0, stream>>>(W, Wq);
        vq_main_kernel<true><<<NTOK / TM, BLOCK, 0, stream>>>(x, W, Wq, b, cb, out, avg);
    } else {
        vq_main_kernel<false><<<NTOK / TM, BLOCK, 0, stream>>>(x, W, nullptr, b, cb, out, avg);
    }
}

// Round 3
// 1729.010 us; speedup vs baseline: 2.5626x; 1.1873x over previous
//
#include <hip/hip_runtime.h>

#define GROUPS 2
#define NUM_VARS 320
#define NVT 640          // GROUPS*NUM_VARS
#define DIM 512
#define VAR_DIM 128
#define NTOK 48000       // B*T
#define TM 32            // tokens per block
#define KC 16            // K-chunk
#define BLOCK 256

// Reorder W[640][512] -> Wq[k/4][640][4] so a K-chunk is one contiguous slab
// and inner-loop float4 LDS reads are consecutive-lane-consecutive-address.
__global__ void make_wq_kernel(const float* __restrict__ W, float* __restrict__ Wq) {
    int f = blockIdx.x * blockDim.x + threadIdx.x;
    if (f >= NVT * DIM) return;
    int kl = f & 3;
    int v  = (f >> 2) % NVT;
    int kq = f / (NVT * 4);
    Wq[f] = W[(size_t)v * DIM + kq * 4 + kl];
}

// __launch_bounds__(256, 3): without it the backend budgets VGPRs for an
// assumed 1024-thread workgroup (-> 8 waves/SIMD -> 64-VGPR clamp) and spills
// the 80-float accumulator to scratch (R1/R2 measured 19.8/5.7 GB HBM scratch
// writes). 3 waves/EU -> 168 VGPR budget; LDS (45.5 KB) caps us at 3 blocks/CU
// = 3 waves/SIMD anyway, so this costs no occupancy.
template <bool USE_WQ>
__global__ __launch_bounds__(BLOCK, 3)
void vq_main_kernel(const float* __restrict__ x,
                    const float* __restrict__ W,
                    const float* __restrict__ Wq,
                    const float* __restrict__ bias,
                    const float* __restrict__ codebook,
                    float* __restrict__ out,
                    float* __restrict__ avg_out) {
    __shared__ float w_s[KC * NVT];   // layout [kq][v][4]  (40 KB)
    __shared__ float x_s[TM][KC];     // [tok][kk]          (2 KB)
    __shared__ float avg_s[NVT];      // block partial softmax sums

    const int tid = threadIdx.x;
    const int tx  = tid & 63;         // lane
    const int ty  = tid >> 6;         // wave id 0..3
    const int n0  = blockIdx.x * TM;

    float acc[8][10];
#pragma unroll
    for (int t = 0; t < 8; ++t)
#pragma unroll
        for (int j = 0; j < 10; ++j) acc[t][j] = 0.f;

    for (int i = tid; i < NVT; i += BLOCK) avg_s[i] = 0.f;

    for (int k0 = 0; k0 < DIM; k0 += KC) {
        __syncthreads();
        if (USE_WQ) {
            const float4* src = (const float4*)(Wq + (size_t)k0 * NVT);
            float4* dst = (float4*)w_s;
#pragma unroll
            for (int i = 0; i < KC * NVT / 4 / BLOCK; ++i)   // 10 float4 each
                dst[tid + i * BLOCK] = src[tid + i * BLOCK];
        } else {
            // fallback: scratch too small for Wq — strided reads (slow, correct)
            for (int i = tid; i < KC * NVT; i += BLOCK) {
                int kl = i & 3;
                int v  = (i >> 2) % NVT;
                int kq = i / (NVT * 4);
                w_s[i] = W[(size_t)v * DIM + k0 + kq * 4 + kl];
            }
        }
        {
            int tok = tid >> 2, q = tid & 3;
            if (tid < TM * 4)
                *(float4*)&x_s[tok][q * 4] =
                    *(const float4*)(x + (size_t)(n0 + tok) * DIM + k0 + q * 4);
        }
        __syncthreads();

        const float4* w4 = (const float4*)w_s;
#pragma unroll
        for (int kq = 0; kq < KC / 4; ++kq) {
            float4 wv[10];
#pragma unroll
            for (int j = 0; j < 10; ++j) wv[j] = w4[kq * NVT + tx + 64 * j];
#pragma unroll
            for (int t = 0; t < 8; ++t) {
                float4 xv = *(const float4*)&x_s[ty * 8 + t][kq * 4];
#pragma unroll
                for (int j = 0; j < 10; ++j) {
                    acc[t][j] = fmaf(xv.x, wv[j].x, acc[t][j]);
                    acc[t][j] = fmaf(xv.y, wv[j].y, acc[t][j]);
                    acc[t][j] = fmaf(xv.z, wv[j].z, acc[t][j]);
                    acc[t][j] = fmaf(xv.w, wv[j].w, acc[t][j]);
                }
            }
        }
    }

    // bias (zeros in harness, kept for generality)
#pragma unroll
    for (int j = 0; j < 10; ++j) {
        float bv = bias[tx + 64 * j];
#pragma unroll
        for (int t = 0; t < 8; ++t) acc[t][j] += bv;
    }

    // Epilogue: each wave owns 8 tokens (all 640 vars spread over its 64 lanes).
    // MUST be fully unrolled: any runtime index into acc[] demotes it to scratch
    // (rule #20 — R1 measured 19.8 GB of HBM scratch writes from exactly this).
#pragma unroll
    for (int t = 0; t < 8; ++t) {
        const int n = n0 + ty * 8 + t;
#pragma unroll
        for (int g = 0; g < GROUPS; ++g) {
            // local top-2 over this lane's 5 values of group g
            float v1 = -3.4e38f, v2 = -3.4e38f;
            int   i1 = 0x7fffffff, i2 = 0x7fffffff;
#pragma unroll
            for (int jj = 0; jj < 5; ++jj) {
                float val = acc[t][g * 5 + jj];
                int   vv  = tx + 64 * jj;      // index within group
                if ((val > v1) || (val == v1 && vv < i1)) {
                    v2 = v1; i2 = i1; v1 = val; i1 = vv;
                } else if ((val > v2) || (val == v2 && vv < i2)) {
                    v2 = val; i2 = vv;
                }
            }
            // wave butterfly top-2 merge
#pragma unroll
            for (int off = 32; off >= 1; off >>= 1) {
                float o1 = __shfl_xor(v1, off);
                int  oi1 = __shfl_xor(i1, off);
                float o2 = __shfl_xor(v2, off);
                int  oi2 = __shfl_xor(i2, off);
                if ((o1 > v1) || (o1 == v1 && oi1 < i1)) { v2 = v1; i2 = i1; v1 = o1; i1 = oi1; }
                else if ((o1 > v2) || (o1 == v2 && oi1 < i2)) { v2 = o1; i2 = oi1; }
                if ((o2 > v1) || (o2 == v1 && oi2 < i1)) { v2 = v1; i2 = i1; v1 = o2; i1 = oi2; }
                else if ((o2 > v2) || (o2 == v2 && oi2 < i2)) { v2 = o2; i2 = oi2; }
            }

            // softmax (fp32, max = v1)
            float m = v1, s = 0.f;
            float e[5];
#pragma unroll
            for (int jj = 0; jj < 5; ++jj) {
                e[jj] = expf(acc[t][g * 5 + jj] - m);
                s += e[jj];
            }
#pragma unroll
            for (int off = 32; off >= 1; off >>= 1) s += __shfl_xor(s, off);
            float inv = 1.f / s;
#pragma unroll
            for (int jj = 0; jj < 5; ++jj)
                atomicAdd(&avg_s[g * NUM_VARS + tx + 64 * jj], e[jj] * inv);

            // Argmax robustness: fp32 summation-order noise is ~1e-3 while the
            // typical top1-top2 gap is ~6.6 (logits sigma ~22.6). Only when the
            // gap is tiny do we re-verify the two candidates in f64. v1/v2 are
            // wave-uniform after the butterfly -> uniform branch, ~0.8% taken.
            int kbest = i1;
            if (v1 - v2 <= 0.05f) {
                const float* xrow = x + (size_t)n * DIM;
                const float* w1r  = W + (size_t)(g * NUM_VARS + i1) * DIM;
                const float* w2r  = W + (size_t)(g * NUM_VARS + i2) * DIM;
                double d1 = 0.0, d2 = 0.0;
                for (int k = tx; k < DIM; k += 64) {
                    double xv = (double)xrow[k];
                    d1 += xv * (double)w1r[k];
                    d2 += xv * (double)w2r[k];
                }
#pragma unroll
                for (int off = 32; off >= 1; off >>= 1) {
                    d1 += __shfl_xor(d1, off);
                    d2 += __shfl_xor(d2, off);
                }
                d1 += (double)bias[g * NUM_VARS + i1];
                d2 += (double)bias[g * NUM_VARS + i2];
                kbest = (d2 > d1 || (d2 == d1 && i2 < i1)) ? i2 : i1;
            }

            // gather codebook row -> out (float2 per lane, coalesced 512B)
            const float2 cbv = *(const float2*)(codebook +
                                (size_t)(g * NUM_VARS + kbest) * VAR_DIM + 2 * tx);
            *(float2*)(out + (size_t)n * (GROUPS * VAR_DIM) + g * VAR_DIM + 2 * tx) = cbv;
        }
    }

    __syncthreads();
    const float scale = 1.f / (float)NTOK;
    for (int i = tid; i < NVT; i += BLOCK)
        atomicAdd(&avg_out[i], avg_s[i] * scale);
}

extern "C" void kernel_launch(void* const* d_in, const int* in_sizes, int n_in,
                              void* d_out, int out_size, void* d_ws, size_t ws_size,
                              hipStream_t stream) {
    const float* x  = (const float*)d_in[0];
    const float* W  = (const float*)d_in[1];
    const float* b  = (const float*)d_in[2];
    const float* cb = (const float*)d_in[3];
    float* out = (float*)d_out;
    float* avg = out + (size_t)NTOK * GROUPS * VAR_DIM;   // avg_probs tail [2*320]

    hipMemsetAsync(avg, 0, NVT * sizeof(float), stream);

    const size_t wq_bytes = (size_t)NVT * DIM * sizeof(float);
    if (ws_size >= wq_bytes) {
        float* Wq = (float*)d_ws;
        make_wq_kernel<<<(NVT * DIM + 255) / 256, 256, 0, stream>>>(W, Wq);
        vq_main_kernel<true><<<NTOK / TM, BLOCK, 0, stream>>>(x, W, Wq, b, cb, out, avg);
    } else {
        vq_main_kernel<false><<<NTOK / TM, BLOCK, 0, stream>>>(x, W, nullptr, b, cb, out, avg);
    }
}